// Round 9
// baseline (165.559 us; speedup 1.0000x reference)
//
#include <hip/hip_runtime.h>
#include <hip/hip_bf16.h>

#define EMBED 1024
#define WINDOW 512
#define NROWS 16384  // 4 * 4096

typedef __attribute__((ext_vector_type(4))) float f32x4;
typedef __bf16 bf16x8 __attribute__((ext_vector_type(8)));

#define GLDS(g, l)                                                        \
  __builtin_amdgcn_global_load_lds(                                       \
      (const __attribute__((address_space(1))) void*)(const void*)(g),    \
      (__attribute__((address_space(3))) void*)(void*)(l), 16, 0, 0)

// ---------------- prep: fp32 -> bf16 cast, 8 elems/thread ----------------
__global__ __launch_bounds__(256) void cast_bf16_kernel(
    const float* __restrict__ in, __bf16* __restrict__ out, int n8) {
  int i = blockIdx.x * blockDim.x + threadIdx.x;
  if (i >= n8) return;
  const f32x4* p = (const f32x4*)(in + (size_t)i * 8);
  f32x4 a = p[0], b = p[1];
  bf16x8 o = {(__bf16)a[0], (__bf16)a[1], (__bf16)a[2], (__bf16)a[3],
              (__bf16)b[0], (__bf16)b[1], (__bf16)b[2], (__bf16)b[3]};
  *(bf16x8*)(out + (size_t)i * 8) = o;
}

// ---------------- prep: MB [512][1024] fp32 -> MB^T [1024][512] bf16 ------
__global__ __launch_bounds__(256) void transpose_mb_kernel(
    const float* __restrict__ mb, __bf16* __restrict__ mbt) {
  int idx = blockIdx.x * blockDim.x + threadIdx.x;  // over 512*1024
  int w = idx >> 10, d = idx & 1023;
  mbt[(size_t)d * WINDOW + w] = (__bf16)mb[idx];
}

// ---------------- softmax in-place on S1 rows (512 wide) -----------------
__global__ __launch_bounds__(256) void softmax_kernel(__bf16* __restrict__ s1) {
  const int row = blockIdx.x * 4 + (threadIdx.x >> 6);
  const int lane = threadIdx.x & 63;
  __bf16* p = s1 + (size_t)row * WINDOW + lane * 8;
  bf16x8 v = *(const bf16x8*)p;
  float f[8];
  float mx = -1e30f;
#pragma unroll
  for (int j = 0; j < 8; ++j) {
    f[j] = (float)v[j] * 0.03125f;  // 1/sqrt(1024)
    mx = fmaxf(mx, f[j]);
  }
#pragma unroll
  for (int off = 1; off < 64; off <<= 1) mx = fmaxf(mx, __shfl_xor(mx, off));
  float s = 0.f;
#pragma unroll
  for (int j = 0; j < 8; ++j) {
    f[j] = __expf(f[j] - mx);
    s += f[j];
  }
#pragma unroll
  for (int off = 1; off < 64; off <<= 1) s += __shfl_xor(s, off);
  const float inv = 1.0f / s;
  bf16x8 o;
#pragma unroll
  for (int j = 0; j < 8; ++j) o[j] = (__bf16)(f[j] * inv);
  *(bf16x8*)p = o;
}

// ---------------- scores kernel (R5 structure, known-good) ---------------
#define SLOADFRAGS(cb, kk)                                                    \
  {                                                                           \
    const __bf16* As_ = &ldsA[cb][(warp_m * 64 + fr) * 64];                   \
    const __bf16* Bs_ = &ldsB[cb][(warp_n * 64 + fr) * 64];                   \
    const int pg_ = (((kk)*4 + fq) ^ (fr & 7)) * 8;                           \
    _Pragma("unroll") for (int m = 0; m < 4; ++m)                             \
        af[m] = *(const bf16x8*)(As_ + m * 16 * 64 + pg_);                    \
    _Pragma("unroll") for (int n = 0; n < 4; ++n)                             \
        bfv[n] = *(const bf16x8*)(Bs_ + n * 16 * 64 + pg_);                   \
  }

#define SMFMA16(ACC)                                                          \
  {                                                                           \
    __builtin_amdgcn_s_barrier();                                             \
    asm volatile("s_waitcnt lgkmcnt(0)" ::: "memory");                        \
    __builtin_amdgcn_s_setprio(1);                                            \
    _Pragma("unroll") for (int m = 0; m < 4; ++m)                             \
        _Pragma("unroll") for (int n = 0; n < 4; ++n)                         \
            ACC[m][n] = __builtin_amdgcn_mfma_f32_16x16x32_bf16(              \
                af[m], bfv[n], ACC[m][n], 0, 0, 0);                           \
    __builtin_amdgcn_s_setprio(0);                                            \
    __builtin_amdgcn_s_barrier();                                             \
  }

__global__ __launch_bounds__(512, 2) void gemm_scores_kernel(
    const __bf16* __restrict__ xb, const __bf16* __restrict__ mbb,
    __bf16* __restrict__ s1) {
  __shared__ __align__(16) __bf16 ldsA[3][256 * 64];
  __shared__ __align__(16) __bf16 ldsB[3][128 * 64];
  const int tid = threadIdx.x;
  const int lane = tid & 63;
  const int wave = tid >> 6;
  const int bid = blockIdx.x;            // 256 blocks
  const int xcd = bid & 7;
  const int idx = bid >> 3;              // 0..31
  const int bm = xcd * 8 + (idx & 7);    // 0..63
  const int bn = idx >> 3;               // 0..3
  const int row0 = bm * 256;
  const int col0 = bn * 128;
  const int warp_m = wave >> 1;
  const int warp_n = wave & 1;
  const int srow = lane >> 3;
  const int sgc = (lane & 7) ^ srow;
  const int wv32 = wave * 32;
  const int wv16 = wave * 16;
  const int fr = lane & 15;
  const int fq = lane >> 4;

  const __bf16* aS = xb + (size_t)(row0 + wv32 + srow) * EMBED + sgc * 8;
  const __bf16* bS = mbb + (size_t)(col0 + wv16 + srow) * EMBED + sgc * 8;

#define STAGE_S1(vt, buf)                                                     \
  {                                                                           \
    const int k0_ = (vt)*64;                                                  \
    _Pragma("unroll") for (int c = 0; c < 2; ++c)                             \
        GLDS(aS + (size_t)c * 8 * EMBED + k0_, &ldsA[buf][(wv32 + c * 8) * 64]); \
    GLDS(bS + k0_, &ldsB[buf][wv16 * 64]);                                    \
  }
#define STAGE_S2(vt, buf)                                                     \
  {                                                                           \
    const int k0_ = (vt)*64;                                                  \
    _Pragma("unroll") for (int c = 2; c < 4; ++c)                             \
        GLDS(aS + (size_t)c * 8 * EMBED + k0_, &ldsA[buf][(wv32 + c * 8) * 64]); \
    GLDS(bS + (size_t)8 * EMBED + k0_, &ldsB[buf][(wv16 + 8) * 64]);          \
  }

  f32x4 acc[4][4];
#pragma unroll
  for (int m = 0; m < 4; ++m)
#pragma unroll
    for (int n = 0; n < 4; ++n) acc[m][n] = (f32x4){0.f, 0.f, 0.f, 0.f};
  bf16x8 af[4], bfv[4];

  STAGE_S1(0, 0); STAGE_S2(0, 0);
  STAGE_S1(1, 1); STAGE_S2(1, 1);
  asm volatile("s_waitcnt vmcnt(6)" ::: "memory");
  __builtin_amdgcn_s_barrier();

  const int NT = 16;
  for (int vt = 0; vt < NT; ++vt) {
    const int cb = vt % 3;
    const int nb = (vt + 2) % 3;
    SLOADFRAGS(cb, 0);
    if (vt + 2 < NT) STAGE_S1(vt + 2, nb);
    SMFMA16(acc);
    SLOADFRAGS(cb, 1);
    if (vt + 2 < NT) STAGE_S2(vt + 2, nb);
    if (vt < NT - 2) {
      asm volatile("s_waitcnt vmcnt(6)" ::: "memory");
    } else if (vt == NT - 2) {
      asm volatile("s_waitcnt vmcnt(0)" ::: "memory");
    }
    SMFMA16(acc);
  }
#undef STAGE_S1
#undef STAGE_S2

#pragma unroll
  for (int n = 0; n < 4; ++n) {
    const int col = col0 + warp_n * 64 + n * 16 + fr;
#pragma unroll
    for (int m = 0; m < 4; ++m)
#pragma unroll
      for (int j = 0; j < 4; ++j) {
        const int row = row0 + warp_m * 64 + m * 16 + fq * 4 + j;
        s1[(size_t)row * WINDOW + col] = (__bf16)acc[m][n][j];
      }
  }
}

// ===== fused dual GEMM + blend: 8 waves, 256x256, wave tile 128x64 =======
// R8's exact schedule (BK=64 dbuf, STG -> vmcnt(8) -> bar -> COMPUTE -> bar,
// 64-elem rows, proven swizzle pair), geometry upgraded so each wave does
// 12 ds_reads per 32 MFMA (MFMA-bound) instead of 8 per 16 (LDS-bound).
// vt 0..7: retrieved (A=s1,B=mbt,K=512) -> accr, parked as packed bf16.
// vt 8..23: gate (A=xb,B=gwb,K=1024) -> accg. Blend epilogue.
__global__ __launch_bounds__(512, 2) void dual_fused256_kernel(
    const __bf16* __restrict__ s1, const __bf16* __restrict__ xb,
    const __bf16* __restrict__ mbt, const __bf16* __restrict__ gwb,
    const float* __restrict__ gb, float* __restrict__ out) {
  __shared__ __align__(16) __bf16 ldsA[2][256 * 64];  // 64 KB
  __shared__ __align__(16) __bf16 ldsB[2][256 * 64];  // 64 KB
  const int tid = threadIdx.x, lane = tid & 63, wave = tid >> 6;
  const int bid = blockIdx.x;                       // 256 blocks
  const int bm = (bid & 7) * 8 + ((bid >> 3) & 7);  // 0..63 XCD-grouped
  const int bn = bid >> 6;                          // 0..3
  const int row0 = bm * 256, col0 = bn * 256;
  const int warp_m = wave >> 2;            // 0..1 -> 128 rows
  const int warp_n = wave & 3;             // 0..3 -> 64 cols
  const int fr = lane & 15, fq = lane >> 4;
  const int srow = lane >> 3;              // 0..7
  const int sgc = (lane & 7) ^ srow;       // pre-swizzled source granule
  const int wv32 = wave * 32;

  const __bf16* aR = s1 + (size_t)(row0 + wv32 + srow) * WINDOW + sgc * 8;
  const __bf16* bR = mbt + (size_t)(col0 + wv32 + srow) * WINDOW + sgc * 8;
  const __bf16* aG = xb + (size_t)(row0 + wv32 + srow) * EMBED + sgc * 8;
  const __bf16* bG = gwb + (size_t)(col0 + wv32 + srow) * EMBED + sgc * 8;

  // per wave per tile: 4 A-glds + 4 B-glds (8 rows each), rows wv32..+31
#define STG(vt, buf)                                                          \
  {                                                                           \
    if ((vt) < 8) {                                                           \
      const int k0_ = (vt)*64;                                                \
      _Pragma("unroll") for (int c = 0; c < 4; ++c)                           \
          GLDS(aR + (size_t)c * 8 * WINDOW + k0_,                             \
               &ldsA[buf][(wv32 + c * 8) * 64]);                              \
      _Pragma("unroll") for (int c = 0; c < 4; ++c)                           \
          GLDS(bR + (size_t)c * 8 * WINDOW + k0_,                             \
               &ldsB[buf][(wv32 + c * 8) * 64]);                              \
    } else {                                                                  \
      const int k0_ = ((vt)-8) * 64;                                          \
      _Pragma("unroll") for (int c = 0; c < 4; ++c)                           \
          GLDS(aG + (size_t)c * 8 * EMBED + k0_,                              \
               &ldsA[buf][(wv32 + c * 8) * 64]);                              \
      _Pragma("unroll") for (int c = 0; c < 4; ++c)                           \
          GLDS(bG + (size_t)c * 8 * EMBED + k0_,                              \
               &ldsB[buf][(wv32 + c * 8) * 64]);                              \
    }                                                                         \
  }

#define BARF                                                                  \
  {                                                                           \
    asm volatile("" ::: "memory");                                            \
    __builtin_amdgcn_s_barrier();                                             \
    asm volatile("" ::: "memory");                                            \
  }

  // per kk: B frags (4 reads) + A in two halves of 4 (8 reads), 32 MFMA.
#define COMPUTE(ACC, cur)                                                     \
  {                                                                           \
    const __bf16* As_ = &ldsA[cur][(warp_m * 128 + fr) * 64];                 \
    const __bf16* Bs_ = &ldsB[cur][(warp_n * 64 + fr) * 64];                  \
    _Pragma("unroll") for (int kk = 0; kk < 2; ++kk) {                        \
      const int pg_ = ((kk * 4 + fq) ^ (fr & 7)) * 8;                         \
      bf16x8 af[4], bfv[4];                                                   \
      _Pragma("unroll") for (int n = 0; n < 4; ++n)                           \
          bfv[n] = *(const bf16x8*)(Bs_ + n * 16 * 64 + pg_);                 \
      _Pragma("unroll") for (int m = 0; m < 4; ++m)                           \
          af[m] = *(const bf16x8*)(As_ + m * 16 * 64 + pg_);                  \
      __builtin_amdgcn_s_setprio(1);                                          \
      _Pragma("unroll") for (int m = 0; m < 4; ++m)                           \
          _Pragma("unroll") for (int n = 0; n < 4; ++n)                       \
              ACC[m][n] = __builtin_amdgcn_mfma_f32_16x16x32_bf16(            \
                  af[m], bfv[n], ACC[m][n], 0, 0, 0);                         \
      __builtin_amdgcn_s_setprio(0);                                          \
      _Pragma("unroll") for (int m = 0; m < 4; ++m)                           \
          af[m] = *(const bf16x8*)(As_ + (64 + m * 16) * 64 + pg_);           \
      __builtin_amdgcn_s_setprio(1);                                          \
      _Pragma("unroll") for (int m = 0; m < 4; ++m)                           \
          _Pragma("unroll") for (int n = 0; n < 4; ++n)                       \
              ACC[4 + m][n] = __builtin_amdgcn_mfma_f32_16x16x32_bf16(        \
                  af[m], bfv[n], ACC[4 + m][n], 0, 0, 0);                     \
      __builtin_amdgcn_s_setprio(0);                                          \
    }                                                                         \
  }

  f32x4 accr[8][4];
#pragma unroll
  for (int m = 0; m < 8; ++m)
#pragma unroll
    for (int n = 0; n < 4; ++n) accr[m][n] = (f32x4){0.f, 0.f, 0.f, 0.f};

  STG(0, 0);
  // retrieved: vt 0..7
  for (int vt = 0; vt < 8; ++vt) {
    const int cur = vt & 1;
    STG(vt + 1, cur ^ 1);
    asm volatile("s_waitcnt vmcnt(8)" ::: "memory");  // tile-vt loads done
    BARF;
    COMPUTE(accr, cur);
    BARF;  // all reads of buf cur done before next STG overwrites it
  }

  // park retrieved as packed bf16 (2 f32 -> 1 u32): 64 VGPR
  unsigned pk[8][4][2];
#pragma unroll
  for (int m = 0; m < 8; ++m)
#pragma unroll
    for (int n = 0; n < 4; ++n) {
      unsigned b0 = (unsigned)__builtin_bit_cast(unsigned short, (__bf16)accr[m][n][0]);
      unsigned b1 = (unsigned)__builtin_bit_cast(unsigned short, (__bf16)accr[m][n][1]);
      unsigned b2 = (unsigned)__builtin_bit_cast(unsigned short, (__bf16)accr[m][n][2]);
      unsigned b3 = (unsigned)__builtin_bit_cast(unsigned short, (__bf16)accr[m][n][3]);
      pk[m][n][0] = (b1 << 16) | b0;
      pk[m][n][1] = (b3 << 16) | b2;
    }

  f32x4 accg[8][4];
#pragma unroll
  for (int m = 0; m < 8; ++m)
#pragma unroll
    for (int n = 0; n < 4; ++n) accg[m][n] = (f32x4){0.f, 0.f, 0.f, 0.f};

  // gate: vt 8..23
  for (int vt = 8; vt < 24; ++vt) {
    const int cur = vt & 1;
    if (vt + 1 < 24) {
      STG(vt + 1, cur ^ 1);
      asm volatile("s_waitcnt vmcnt(8)" ::: "memory");
    } else {
      asm volatile("s_waitcnt vmcnt(0)" ::: "memory");
    }
    BARF;
    COMPUTE(accg, cur);
    BARF;
  }
#undef STG
#undef COMPUTE
#undef BARF

  // epilogue: g = sigmoid(accg + gb); out = g*x + (1-g)*retrieved
#pragma unroll
  for (int n = 0; n < 4; ++n) {
    const int col = col0 + warp_n * 64 + n * 16 + fr;
    const float bias = gb[col];
#pragma unroll
    for (int m = 0; m < 8; ++m) {
      float rv[4];
      rv[0] = __builtin_bit_cast(float, pk[m][n][0] << 16);
      rv[1] = __builtin_bit_cast(float, pk[m][n][0] & 0xffff0000u);
      rv[2] = __builtin_bit_cast(float, pk[m][n][1] << 16);
      rv[3] = __builtin_bit_cast(float, pk[m][n][1] & 0xffff0000u);
#pragma unroll
      for (int j = 0; j < 4; ++j) {
        const int row = row0 + warp_m * 128 + m * 16 + fq * 4 + j;
        const size_t o = (size_t)row * EMBED + col;
        const float g = 1.0f / (1.0f + __expf(-(accg[m][n][j] + bias)));
        const float xv = (float)xb[o];
        out[o] = g * xv + (1.0f - g) * rv[j];
      }
    }
  }
}

extern "C" void kernel_launch(void* const* d_in, const int* in_sizes, int n_in,
                              void* d_out, int out_size, void* d_ws,
                              size_t ws_size, hipStream_t stream) {
  const float* x = (const float*)d_in[0];
  const float* mb = (const float*)d_in[1];
  const float* gw = (const float*)d_in[2];
  const float* gb = (const float*)d_in[3];
  float* out = (float*)d_out;

  char* ws = (char*)d_ws;
  __bf16* xb = (__bf16*)(ws);                   // 16384*1024*2 = 33,554,432
  __bf16* mbb = (__bf16*)(ws + 33554432);       // 512*1024*2  =  1,048,576
  __bf16* mbt = (__bf16*)(ws + 34603008);       // 1024*512*2  =  1,048,576
  __bf16* gwb = (__bf16*)(ws + 35651584);       // 1024*1024*2 =  2,097,152
  __bf16* s1 = (__bf16*)(ws + 37748736);        // 16384*512*2 = 16,777,216
  // total 54,525,952 bytes

  cast_bf16_kernel<<<8192, 256, 0, stream>>>(x, xb, 2097152);
  cast_bf16_kernel<<<256, 256, 0, stream>>>(mb, mbb, 65536);
  cast_bf16_kernel<<<512, 256, 0, stream>>>(gw, gwb, 131072);
  transpose_mb_kernel<<<2048, 256, 0, stream>>>(mb, mbt);
  gemm_scores_kernel<<<256, 512, 0, stream>>>(xb, mbb, s1);
  softmax_kernel<<<4096, 256, 0, stream>>>(s1);
  dual_fused256_kernel<<<256, 512, 0, stream>>>(s1, xb, mbt, gwb, gb, out);
}

// Round 10
// 152.305 us; speedup vs baseline: 1.0870x; 1.0870x over previous
//
#include <hip/hip_runtime.h>
#include <hip/hip_bf16.h>

#define EMBED 1024
#define WINDOW 512
#define NROWS 16384  // 4 * 4096

typedef __attribute__((ext_vector_type(4))) float f32x4;
typedef __bf16 bf16x8 __attribute__((ext_vector_type(8)));

#define GLDS(g, l)                                                        \
  __builtin_amdgcn_global_load_lds(                                       \
      (const __attribute__((address_space(1))) void*)(const void*)(g),    \
      (__attribute__((address_space(3))) void*)(void*)(l), 16, 0, 0)

// ---------------- prep: fp32 -> bf16 cast, 8 elems/thread ----------------
__global__ __launch_bounds__(256) void cast_bf16_kernel(
    const float* __restrict__ in, __bf16* __restrict__ out, int n8) {
  int i = blockIdx.x * blockDim.x + threadIdx.x;
  if (i >= n8) return;
  const f32x4* p = (const f32x4*)(in + (size_t)i * 8);
  f32x4 a = p[0], b = p[1];
  bf16x8 o = {(__bf16)a[0], (__bf16)a[1], (__bf16)a[2], (__bf16)a[3],
              (__bf16)b[0], (__bf16)b[1], (__bf16)b[2], (__bf16)b[3]};
  *(bf16x8*)(out + (size_t)i * 8) = o;
}

// ---------------- prep: MB [512][1024] fp32 -> MB^T [1024][512] bf16 ------
__global__ __launch_bounds__(256) void transpose_mb_kernel(
    const float* __restrict__ mb, __bf16* __restrict__ mbt) {
  int idx = blockIdx.x * blockDim.x + threadIdx.x;  // over 512*1024
  int w = idx >> 10, d = idx & 1023;
  mbt[(size_t)d * WINDOW + w] = (__bf16)mb[idx];
}

// ---------------- softmax in-place on S1 rows (512 wide) -----------------
__global__ __launch_bounds__(256) void softmax_kernel(__bf16* __restrict__ s1) {
  const int row = blockIdx.x * 4 + (threadIdx.x >> 6);
  const int lane = threadIdx.x & 63;
  __bf16* p = s1 + (size_t)row * WINDOW + lane * 8;
  bf16x8 v = *(const bf16x8*)p;
  float f[8];
  float mx = -1e30f;
#pragma unroll
  for (int j = 0; j < 8; ++j) {
    f[j] = (float)v[j] * 0.03125f;  // 1/sqrt(1024)
    mx = fmaxf(mx, f[j]);
  }
#pragma unroll
  for (int off = 1; off < 64; off <<= 1) mx = fmaxf(mx, __shfl_xor(mx, off));
  float s = 0.f;
#pragma unroll
  for (int j = 0; j < 8; ++j) {
    f[j] = __expf(f[j] - mx);
    s += f[j];
  }
#pragma unroll
  for (int off = 1; off < 64; off <<= 1) s += __shfl_xor(s, off);
  const float inv = 1.0f / s;
  bf16x8 o;
#pragma unroll
  for (int j = 0; j < 8; ++j) o[j] = (__bf16)(f[j] * inv);
  *(bf16x8*)p = o;
}

// ---------------- scores kernel (R5 structure, known-good) ---------------
#define SLOADFRAGS(cb, kk)                                                    \
  {                                                                           \
    const __bf16* As_ = &ldsA[cb][(warp_m * 64 + fr) * 64];                   \
    const __bf16* Bs_ = &ldsB[cb][(warp_n * 64 + fr) * 64];                   \
    const int pg_ = (((kk)*4 + fq) ^ (fr & 7)) * 8;                           \
    _Pragma("unroll") for (int m = 0; m < 4; ++m)                             \
        af[m] = *(const bf16x8*)(As_ + m * 16 * 64 + pg_);                    \
    _Pragma("unroll") for (int n = 0; n < 4; ++n)                             \
        bfv[n] = *(const bf16x8*)(Bs_ + n * 16 * 64 + pg_);                   \
  }

#define SMFMA16(ACC)                                                          \
  {                                                                           \
    __builtin_amdgcn_s_barrier();                                             \
    asm volatile("s_waitcnt lgkmcnt(0)" ::: "memory");                        \
    __builtin_amdgcn_s_setprio(1);                                            \
    _Pragma("unroll") for (int m = 0; m < 4; ++m)                             \
        _Pragma("unroll") for (int n = 0; n < 4; ++n)                         \
            ACC[m][n] = __builtin_amdgcn_mfma_f32_16x16x32_bf16(              \
                af[m], bfv[n], ACC[m][n], 0, 0, 0);                           \
    __builtin_amdgcn_s_setprio(0);                                            \
    __builtin_amdgcn_s_barrier();                                             \
  }

__global__ __launch_bounds__(512, 2) void gemm_scores_kernel(
    const __bf16* __restrict__ xb, const __bf16* __restrict__ mbb,
    __bf16* __restrict__ s1) {
  __shared__ __align__(16) __bf16 ldsA[3][256 * 64];
  __shared__ __align__(16) __bf16 ldsB[3][128 * 64];
  const int tid = threadIdx.x;
  const int lane = tid & 63;
  const int wave = tid >> 6;
  const int bid = blockIdx.x;            // 256 blocks
  const int xcd = bid & 7;
  const int idx = bid >> 3;              // 0..31
  const int bm = xcd * 8 + (idx & 7);    // 0..63
  const int bn = idx >> 3;               // 0..3
  const int row0 = bm * 256;
  const int col0 = bn * 128;
  const int warp_m = wave >> 1;
  const int warp_n = wave & 1;
  const int srow = lane >> 3;
  const int sgc = (lane & 7) ^ srow;
  const int wv32 = wave * 32;
  const int wv16 = wave * 16;
  const int fr = lane & 15;
  const int fq = lane >> 4;

  const __bf16* aS = xb + (size_t)(row0 + wv32 + srow) * EMBED + sgc * 8;
  const __bf16* bS = mbb + (size_t)(col0 + wv16 + srow) * EMBED + sgc * 8;

#define STAGE_S1(vt, buf)                                                     \
  {                                                                           \
    const int k0_ = (vt)*64;                                                  \
    _Pragma("unroll") for (int c = 0; c < 2; ++c)                             \
        GLDS(aS + (size_t)c * 8 * EMBED + k0_, &ldsA[buf][(wv32 + c * 8) * 64]); \
    GLDS(bS + k0_, &ldsB[buf][wv16 * 64]);                                    \
  }
#define STAGE_S2(vt, buf)                                                     \
  {                                                                           \
    const int k0_ = (vt)*64;                                                  \
    _Pragma("unroll") for (int c = 2; c < 4; ++c)                             \
        GLDS(aS + (size_t)c * 8 * EMBED + k0_, &ldsA[buf][(wv32 + c * 8) * 64]); \
    GLDS(bS + (size_t)8 * EMBED + k0_, &ldsB[buf][(wv16 + 8) * 64]);          \
  }

  f32x4 acc[4][4];
#pragma unroll
  for (int m = 0; m < 4; ++m)
#pragma unroll
    for (int n = 0; n < 4; ++n) acc[m][n] = (f32x4){0.f, 0.f, 0.f, 0.f};
  bf16x8 af[4], bfv[4];

  STAGE_S1(0, 0); STAGE_S2(0, 0);
  STAGE_S1(1, 1); STAGE_S2(1, 1);
  asm volatile("s_waitcnt vmcnt(6)" ::: "memory");
  __builtin_amdgcn_s_barrier();

  const int NT = 16;
  for (int vt = 0; vt < NT; ++vt) {
    const int cb = vt % 3;
    const int nb = (vt + 2) % 3;
    SLOADFRAGS(cb, 0);
    if (vt + 2 < NT) STAGE_S1(vt + 2, nb);
    SMFMA16(acc);
    SLOADFRAGS(cb, 1);
    if (vt + 2 < NT) STAGE_S2(vt + 2, nb);
    if (vt < NT - 2) {
      asm volatile("s_waitcnt vmcnt(6)" ::: "memory");
    } else if (vt == NT - 2) {
      asm volatile("s_waitcnt vmcnt(0)" ::: "memory");
    }
    SMFMA16(acc);
  }
#undef STAGE_S1
#undef STAGE_S2

#pragma unroll
  for (int n = 0; n < 4; ++n) {
    const int col = col0 + warp_n * 64 + n * 16 + fr;
#pragma unroll
    for (int m = 0; m < 4; ++m)
#pragma unroll
      for (int j = 0; j < 4; ++j) {
        const int row = row0 + warp_m * 64 + m * 16 + fq * 4 + j;
        s1[(size_t)row * WINDOW + col] = (__bf16)acc[m][n][j];
      }
  }
}

// ===== fused dual GEMM + blend: 4 waves, 128x128, BK=32, 4-slot ring =====
// R8's schedule with 3-tile lookahead: slot = 16 KB (A 8K + B 8K), 4 slots
// = 64 KB -> 2 blocks/CU AND ~1500 cy lookahead (> ~900 cy HBM latency).
// Virtual tiles: vt 0..15 retrieved (A=s1,B=mbt,K=512); 16..47 gate
// (A=xb,B=gwb,K=1024). Per wave per tile: 4 glds, 8 ds_read_b128, 16 MFMA,
// 2 barriers. Steady 12 loads in flight; waits vmcnt(8), tail (4)->(0).
// Swizzle (32-el rows, 4 granules): source (lane&3)^(srow&3), read
// fq^(fr&3) — involution; b128 slot pattern <=2-way (free).
__global__ __launch_bounds__(256, 2) void dual_bk32_kernel(
    const __bf16* __restrict__ s1, const __bf16* __restrict__ xb,
    const __bf16* __restrict__ mbt, const __bf16* __restrict__ gwb,
    const float* __restrict__ gb, float* __restrict__ out) {
  __shared__ __align__(16) __bf16 ldsA[4][128 * 32];  // 32 KB
  __shared__ __align__(16) __bf16 ldsB[4][128 * 32];  // 32 KB
  const int tid = threadIdx.x, lane = tid & 63, wave = tid >> 6;
  // XCD-grouped bijection over 1024 blocks
  const int bid = blockIdx.x;
  const int xcd = bid & 7;
  const int g = bid >> 3;                  // 0..127
  const int bm = xcd * 16 + (g & 15);      // 0..127
  const int bn = g >> 4;                   // 0..7
  const int row0 = bm * 128, col0 = bn * 128;
  const int warp_m = wave >> 1, warp_n = wave & 1;  // 2x2 waves, 64x64 tiles
  const int fr = lane & 15, fq = lane >> 4;
  const int srow = lane >> 2;              // 0..15
  const int sgc = (lane & 3) ^ (srow & 3); // pre-swizzled source granule
  const int wv32 = wave * 32;

  const __bf16* aR = s1 + (size_t)(row0 + wv32 + srow) * WINDOW + sgc * 8;
  const __bf16* bR = mbt + (size_t)(col0 + wv32 + srow) * WINDOW + sgc * 8;
  const __bf16* aG = xb + (size_t)(row0 + wv32 + srow) * EMBED + sgc * 8;
  const __bf16* bG = gwb + (size_t)(col0 + wv32 + srow) * EMBED + sgc * 8;

  // per wave per tile: 2 A-glds + 2 B-glds (16 rows each), rows wv32..+31
#define STG(vt, slot)                                                         \
  {                                                                           \
    if ((vt) < 16) {                                                          \
      const int k0_ = (vt)*32;                                                \
      GLDS(aR + k0_, &ldsA[slot][wv32 * 32]);                                 \
      GLDS(aR + (size_t)16 * WINDOW + k0_, &ldsA[slot][(wv32 + 16) * 32]);    \
      GLDS(bR + k0_, &ldsB[slot][wv32 * 32]);                                 \
      GLDS(bR + (size_t)16 * WINDOW + k0_, &ldsB[slot][(wv32 + 16) * 32]);    \
    } else {                                                                  \
      const int k0_ = ((vt)-16) * 32;                                         \
      GLDS(aG + k0_, &ldsA[slot][wv32 * 32]);                                 \
      GLDS(aG + (size_t)16 * EMBED + k0_, &ldsA[slot][(wv32 + 16) * 32]);     \
      GLDS(bG + k0_, &ldsB[slot][wv32 * 32]);                                 \
      GLDS(bG + (size_t)16 * EMBED + k0_, &ldsB[slot][(wv32 + 16) * 32]);     \
    }                                                                         \
  }

#define BARF                                                                  \
  {                                                                           \
    asm volatile("" ::: "memory");                                            \
    __builtin_amdgcn_s_barrier();                                             \
    asm volatile("" ::: "memory");                                            \
  }

  // one K=32 step: 4 A-frags + 4 B-frags (b128, swizzled granule), 16 MFMA
#define COMPUTE(ACC, slot)                                                    \
  {                                                                           \
    const __bf16* As_ = &ldsA[slot][(warp_m * 64 + fr) * 32];                 \
    const __bf16* Bs_ = &ldsB[slot][(warp_n * 64 + fr) * 32];                 \
    const int pg_ = (fq ^ (fr & 3)) * 8;                                      \
    bf16x8 af[4], bfv[4];                                                     \
    _Pragma("unroll") for (int m = 0; m < 4; ++m)                             \
        af[m] = *(const bf16x8*)(As_ + m * 16 * 32 + pg_);                    \
    _Pragma("unroll") for (int n = 0; n < 4; ++n)                             \
        bfv[n] = *(const bf16x8*)(Bs_ + n * 16 * 32 + pg_);                   \
    asm volatile("s_waitcnt lgkmcnt(0)" ::: "memory");                        \
    __builtin_amdgcn_s_setprio(1);                                            \
    _Pragma("unroll") for (int m = 0; m < 4; ++m)                             \
        _Pragma("unroll") for (int n = 0; n < 4; ++n)                         \
            ACC[m][n] = __builtin_amdgcn_mfma_f32_16x16x32_bf16(              \
                af[m], bfv[n], ACC[m][n], 0, 0, 0);                           \
    __builtin_amdgcn_s_setprio(0);                                            \
  }

  f32x4 accr[4][4], accg[4][4];
#pragma unroll
  for (int m = 0; m < 4; ++m)
#pragma unroll
    for (int n = 0; n < 4; ++n) {
      accr[m][n] = (f32x4){0.f, 0.f, 0.f, 0.f};
      accg[m][n] = (f32x4){0.f, 0.f, 0.f, 0.f};
    }

  const int NT = 48;  // 16 retrieved + 32 gate
  STG(0, 0); STG(1, 1); STG(2, 2);  // 12 in flight

  for (int vt = 0; vt < NT; ++vt) {
    const int slot = vt & 3;
    // wait for THIS tile's 4 loads; keep later tiles' loads in flight
    if (vt < NT - 2) {
      asm volatile("s_waitcnt vmcnt(8)" ::: "memory");
    } else if (vt == NT - 2) {
      asm volatile("s_waitcnt vmcnt(4)" ::: "memory");
    } else {
      asm volatile("s_waitcnt vmcnt(0)" ::: "memory");
    }
    BARF;  // all waves' tile-vt stages visible
    if (vt + 3 < NT) STG(vt + 3, (vt + 3) & 3);  // slot reused from vt-1
    if (vt < 16) {
      COMPUTE(accr, slot);
    } else {
      COMPUTE(accg, slot);
    }
    BARF;  // reads of slot done before it is re-staged next iter
  }
#undef STG
#undef COMPUTE
#undef BARF

  // epilogue: g = sigmoid(accg + gb); out = g*x + (1-g)*accr
#pragma unroll
  for (int n = 0; n < 4; ++n) {
    const int col = col0 + warp_n * 64 + n * 16 + fr;
    const float bias = gb[col];
#pragma unroll
    for (int m = 0; m < 4; ++m) {
#pragma unroll
      for (int j = 0; j < 4; ++j) {
        const int row = row0 + warp_m * 64 + m * 16 + fq * 4 + j;
        const size_t o = (size_t)row * EMBED + col;
        const float gt = 1.0f / (1.0f + __expf(-(accg[m][n][j] + bias)));
        const float xv = (float)xb[o];
        out[o] = gt * xv + (1.0f - gt) * accr[m][n][j];
      }
    }
  }
}

extern "C" void kernel_launch(void* const* d_in, const int* in_sizes, int n_in,
                              void* d_out, int out_size, void* d_ws,
                              size_t ws_size, hipStream_t stream) {
  const float* x = (const float*)d_in[0];
  const float* mb = (const float*)d_in[1];
  const float* gw = (const float*)d_in[2];
  const float* gb = (const float*)d_in[3];
  float* out = (float*)d_out;

  char* ws = (char*)d_ws;
  __bf16* xb = (__bf16*)(ws);                   // 16384*1024*2 = 33,554,432
  __bf16* mbb = (__bf16*)(ws + 33554432);       // 512*1024*2  =  1,048,576
  __bf16* mbt = (__bf16*)(ws + 34603008);       // 1024*512*2  =  1,048,576
  __bf16* gwb = (__bf16*)(ws + 35651584);       // 1024*1024*2 =  2,097,152
  __bf16* s1 = (__bf16*)(ws + 37748736);        // 16384*512*2 = 16,777,216
  // total 54,525,952 bytes

  cast_bf16_kernel<<<8192, 256, 0, stream>>>(x, xb, 2097152);
  cast_bf16_kernel<<<256, 256, 0, stream>>>(mb, mbb, 65536);
  cast_bf16_kernel<<<512, 256, 0, stream>>>(gw, gwb, 131072);
  transpose_mb_kernel<<<2048, 256, 0, stream>>>(mb, mbt);
  gemm_scores_kernel<<<256, 512, 0, stream>>>(xb, mbb, s1);
  softmax_kernel<<<4096, 256, 0, stream>>>(s1);
  dual_bk32_kernel<<<1024, 256, 0, stream>>>(s1, xb, mbt, gwb, gb, out);
}

// Round 11
// 125.441 us; speedup vs baseline: 1.3198x; 1.2142x over previous
//
#include <hip/hip_runtime.h>
#include <hip/hip_bf16.h>

#define EMBED 1024
#define WINDOW 512
#define NROWS 16384  // 4 * 4096

typedef __attribute__((ext_vector_type(4))) float f32x4;
typedef __bf16 bf16x8 __attribute__((ext_vector_type(8)));

#define GLDS(g, l)                                                        \
  __builtin_amdgcn_global_load_lds(                                       \
      (const __attribute__((address_space(1))) void*)(const void*)(g),    \
      (__attribute__((address_space(3))) void*)(void*)(l), 16, 0, 0)

// ---------------- prep: fp32 -> bf16 cast, 8 elems/thread ----------------
__global__ __launch_bounds__(256) void cast_bf16_kernel(
    const float* __restrict__ in, __bf16* __restrict__ out, int n8) {
  int i = blockIdx.x * blockDim.x + threadIdx.x;
  if (i >= n8) return;
  const f32x4* p = (const f32x4*)(in + (size_t)i * 8);
  f32x4 a = p[0], b = p[1];
  bf16x8 o = {(__bf16)a[0], (__bf16)a[1], (__bf16)a[2], (__bf16)a[3],
              (__bf16)b[0], (__bf16)b[1], (__bf16)b[2], (__bf16)b[3]};
  *(bf16x8*)(out + (size_t)i * 8) = o;
}

// ---------------- prep: MB [512][1024] fp32 -> MB^T [1024][512] bf16 ------
__global__ __launch_bounds__(256) void transpose_mb_kernel(
    const float* __restrict__ mb, __bf16* __restrict__ mbt) {
  int idx = blockIdx.x * blockDim.x + threadIdx.x;  // over 512*1024
  int w = idx >> 10, d = idx & 1023;
  mbt[(size_t)d * WINDOW + w] = (__bf16)mb[idx];
}

// ============== scores + softmax + x-cast mega kernel ====================
// Block = 64 rows x 512 cols (full row -> in-block softmax). 512 thr, 8
// waves, wave tile 64x64, BK=32, dbuf. A (x rows) reg-staged from f32
// (cast in regs, ds_write + xb global store byproduct). B (mbb) via glds.
// Swizzle for 64B rows (3-term, residual 2-way = free):
//   stored granule g' = g ^ f(row), f(r) = (r&3)^((r>>2)&3)
//   read granule     = fq ^ f(fr)
__global__ __launch_bounds__(512, 2) void scores_mega_kernel(
    const float* __restrict__ x, const __bf16* __restrict__ mbb,
    __bf16* __restrict__ xb, __bf16* __restrict__ s1) {
  __shared__ __align__(16) __bf16 ldsA[2][64 * 32];   // 8 KB
  __shared__ __align__(16) __bf16 ldsB[2][512 * 32];  // 64 KB
  __shared__ float sred[8][64];                       // 2 KB
  __shared__ float sfin[64];
  const int tid = threadIdx.x, lane = tid & 63, wave = tid >> 6;
  const int row0 = blockIdx.x * 64;  // grid 256
  const int warp_n = wave;           // cols wave*64..+63
  const int fr = lane & 15, fq = lane >> 4;

  // A reg-stage map: thread -> row tid>>3, 4 elems at (tid&7)*4
  const int arow = tid >> 3;
  const int acol4 = (tid & 7) * 4;
  const int ag = (tid >> 1) & 3;  // granule = (tid&7)>>1
  const int ah = tid & 1;         // half within granule
  const int fA = (arow & 3) ^ ((arow >> 2) & 3);
  const int aws = arow * 32 + ((ag ^ fA) * 8) + ah * 4;  // LDS elem offset
  const float* aSrc = x + (size_t)(row0 + arow) * EMBED + acol4;
  __bf16* xbDst = xb + (size_t)(row0 + arow) * EMBED + acol4;

  // B glds map: per wave 4 glds, each 16 rows x 4 granules (1024 B)
  const int srow = lane >> 2;  // 0..15
  const int sgc = (lane & 3) ^ ((lane >> 2) & 3) ^ ((lane >> 4) & 3);
  const __bf16* bSrc = mbb + (size_t)(wave * 64 + srow) * EMBED + sgc * 8;

#define STG_B(t, buf)                                                         \
  {                                                                           \
    _Pragma("unroll") for (int c = 0; c < 4; ++c)                             \
        GLDS(bSrc + (size_t)c * 16 * EMBED + (t) * 32,                        \
             &ldsB[buf][(wave * 64 + c * 16) * 32]);                          \
  }

#define PACK_WRITE(av, buf, t)                                                \
  {                                                                           \
    unsigned u0 =                                                             \
        ((unsigned)__builtin_bit_cast(unsigned short, (__bf16)av[1]) << 16) | \
        (unsigned)__builtin_bit_cast(unsigned short, (__bf16)av[0]);          \
    unsigned u1 =                                                             \
        ((unsigned)__builtin_bit_cast(unsigned short, (__bf16)av[3]) << 16) | \
        (unsigned)__builtin_bit_cast(unsigned short, (__bf16)av[2]);          \
    uint2 w2 = {u0, u1};                                                      \
    *(uint2*)(&ldsA[buf][aws]) = w2;                                          \
    *(uint2*)(xbDst + (t) * 32) = w2;                                         \
  }

#define MCOMPUTE(cur)                                                         \
  {                                                                           \
    const __bf16* As_ = &ldsA[cur][0];                                        \
    const __bf16* Bs_ = &ldsB[cur][(warp_n * 64) * 32];                       \
    const int pg_ = (fq ^ ((fr & 3) ^ ((fr >> 2) & 3))) * 8;                  \
    bf16x8 af[4], bfv[4];                                                     \
    _Pragma("unroll") for (int m = 0; m < 4; ++m)                             \
        af[m] = *(const bf16x8*)(As_ + (m * 16 + fr) * 32 + pg_);             \
    _Pragma("unroll") for (int n = 0; n < 4; ++n)                             \
        bfv[n] = *(const bf16x8*)(Bs_ + (n * 16 + fr) * 32 + pg_);            \
    asm volatile("s_waitcnt lgkmcnt(0)" ::: "memory");                        \
    __builtin_amdgcn_s_setprio(1);                                            \
    _Pragma("unroll") for (int m = 0; m < 4; ++m)                             \
        _Pragma("unroll") for (int n = 0; n < 4; ++n)                         \
            acc[m][n] = __builtin_amdgcn_mfma_f32_16x16x32_bf16(              \
                af[m], bfv[n], acc[m][n], 0, 0, 0);                           \
    __builtin_amdgcn_s_setprio(0);                                            \
  }

  f32x4 acc[4][4];
#pragma unroll
  for (int m = 0; m < 4; ++m)
#pragma unroll
    for (int n = 0; n < 4; ++n) acc[m][n] = (f32x4){0.f, 0.f, 0.f, 0.f};

  // prologue: stage tile 0
  {
    f32x4 a0 = *(const f32x4*)(aSrc);
    asm volatile("" ::: "memory");
    STG_B(0, 0);
    asm volatile("s_waitcnt vmcnt(0)" ::: "memory");
    PACK_WRITE(a0, 0, 0);
    asm volatile("s_waitcnt lgkmcnt(0)" ::: "memory");
    __builtin_amdgcn_s_barrier();
  }

  for (int t = 0; t < 32; ++t) {
    const int cur = t & 1;
    f32x4 an;
    if (t + 1 < 32) {
      an = *(const f32x4*)(aSrc + (t + 1) * 32);  // issued FIRST
      asm volatile("" ::: "memory");              // pin order vs glds
      STG_B(t + 1, cur ^ 1);
    }
    MCOMPUTE(cur);
    if (t + 1 < 32) {
      asm volatile("s_waitcnt vmcnt(4)" ::: "memory");  // A f32 arrived
      PACK_WRITE(an, cur ^ 1, t + 1);
      asm volatile("s_waitcnt vmcnt(0)" ::: "memory");  // B(t+1) in LDS
      asm volatile("s_waitcnt lgkmcnt(0)" ::: "memory");
    }
    __builtin_amdgcn_s_barrier();
  }
#undef STG_B
#undef PACK_WRITE
#undef MCOMPUTE

  // -------- softmax epilogue (full 512-col rows in block) ----------------
  const float scale = 0.03125f;  // 1/sqrt(1024)
  float rmx[4][4];
#pragma unroll
  for (int m = 0; m < 4; ++m)
#pragma unroll
    for (int j = 0; j < 4; ++j) {
      float v = -1e30f;
#pragma unroll
      for (int n = 0; n < 4; ++n) {
        acc[m][n][j] *= scale;
        v = fmaxf(v, acc[m][n][j]);
      }
      rmx[m][j] = v;
    }
#pragma unroll
  for (int off = 1; off < 16; off <<= 1)
#pragma unroll
    for (int m = 0; m < 4; ++m)
#pragma unroll
      for (int j = 0; j < 4; ++j)
        rmx[m][j] = fmaxf(rmx[m][j], __shfl_xor(rmx[m][j], off));
  if (fr == 0) {
#pragma unroll
    for (int m = 0; m < 4; ++m)
#pragma unroll
      for (int j = 0; j < 4; ++j) sred[warp_n][m * 16 + fq * 4 + j] = rmx[m][j];
  }
  __syncthreads();
  if (tid < 64) {
    float v = sred[0][tid];
#pragma unroll
    for (int w = 1; w < 8; ++w) v = fmaxf(v, sred[w][tid]);
    sfin[tid] = v;
  }
  __syncthreads();

  float rsm[4][4];
#pragma unroll
  for (int m = 0; m < 4; ++m)
#pragma unroll
    for (int j = 0; j < 4; ++j) {
      const float fm = sfin[m * 16 + fq * 4 + j];
      float s = 0.f;
#pragma unroll
      for (int n = 0; n < 4; ++n) {
        float e = __expf(acc[m][n][j] - fm);
        acc[m][n][j] = e;
        s += e;
      }
      rsm[m][j] = s;
    }
#pragma unroll
  for (int off = 1; off < 16; off <<= 1)
#pragma unroll
    for (int m = 0; m < 4; ++m)
#pragma unroll
      for (int j = 0; j < 4; ++j) rsm[m][j] += __shfl_xor(rsm[m][j], off);
  if (fr == 0) {
#pragma unroll
    for (int m = 0; m < 4; ++m)
#pragma unroll
      for (int j = 0; j < 4; ++j) sred[warp_n][m * 16 + fq * 4 + j] = rsm[m][j];
  }
  __syncthreads();
  if (tid < 64) {
    float v = sred[0][tid];
#pragma unroll
    for (int w = 1; w < 8; ++w) v += sred[w][tid];
    sfin[tid] = 1.0f / v;
  }
  __syncthreads();

#pragma unroll
  for (int m = 0; m < 4; ++m)
#pragma unroll
    for (int j = 0; j < 4; ++j) {
      const int row = row0 + m * 16 + fq * 4 + j;
      const float inv = sfin[m * 16 + fq * 4 + j];
#pragma unroll
      for (int n = 0; n < 4; ++n)
        s1[(size_t)row * WINDOW + warp_n * 64 + n * 16 + fr] =
            (__bf16)(acc[m][n][j] * inv);
    }
}

// ======= fused dual GEMM + blend: 4 waves, 128x128, dbuf, 2 blocks/CU ====
// R8 structure verbatim; only the grid bijection changed: bn is now the
// INNER index so each bm's A-panel (384 KB) stays L2-hot across its 8 bn.
__global__ __launch_bounds__(256, 2) void dual_fused128_kernel(
    const __bf16* __restrict__ s1, const __bf16* __restrict__ xb,
    const __bf16* __restrict__ mbt, const __bf16* __restrict__ gwb,
    const float* __restrict__ gb, float* __restrict__ out) {
  __shared__ __align__(16) __bf16 ldsA[2][128 * 64];  // 32 KB
  __shared__ __align__(16) __bf16 ldsB[2][128 * 64];  // 32 KB
  const int tid = threadIdx.x, lane = tid & 63, wave = tid >> 6;
  const int bid = blockIdx.x;
  const int xcd = bid & 7;
  const int g = bid >> 3;                  // 0..127
  const int bm = xcd * 16 + (g >> 3);      // bn inner: A-panel L2 locality
  const int bn = g & 7;
  const int row0 = bm * 128, col0 = bn * 128;
  const int warp_m = wave >> 1, warp_n = wave & 1;  // 2x2 waves, 64x64 tiles
  const int fr = lane & 15, fq = lane >> 4;
  const int srow = lane >> 3;              // 0..7
  const int sgc = (lane & 7) ^ srow;       // pre-swizzled source granule
  const int wv32 = wave * 32;

  const __bf16* aR = s1 + (size_t)(row0 + wv32 + srow) * WINDOW + sgc * 8;
  const __bf16* bR = mbt + (size_t)(col0 + wv32 + srow) * WINDOW + sgc * 8;
  const __bf16* aG = xb + (size_t)(row0 + wv32 + srow) * EMBED + sgc * 8;
  const __bf16* bG = gwb + (size_t)(col0 + wv32 + srow) * EMBED + sgc * 8;

#define STG(vt, buf)                                                          \
  {                                                                           \
    if ((vt) < 8) {                                                           \
      const int k0_ = (vt)*64;                                                \
      _Pragma("unroll") for (int c = 0; c < 4; ++c)                           \
          GLDS(aR + (size_t)c * 8 * WINDOW + k0_,                             \
               &ldsA[buf][(wv32 + c * 8) * 64]);                              \
      _Pragma("unroll") for (int c = 0; c < 4; ++c)                           \
          GLDS(bR + (size_t)c * 8 * WINDOW + k0_,                             \
               &ldsB[buf][(wv32 + c * 8) * 64]);                              \
    } else {                                                                  \
      const int k0_ = ((vt)-8) * 64;                                          \
      _Pragma("unroll") for (int c = 0; c < 4; ++c)                           \
          GLDS(aG + (size_t)c * 8 * EMBED + k0_,                              \
               &ldsA[buf][(wv32 + c * 8) * 64]);                              \
      _Pragma("unroll") for (int c = 0; c < 4; ++c)                           \
          GLDS(bG + (size_t)c * 8 * EMBED + k0_,                              \
               &ldsB[buf][(wv32 + c * 8) * 64]);                              \
    }                                                                         \
  }

#define BARF                                                                  \
  {                                                                           \
    asm volatile("" ::: "memory");                                            \
    __builtin_amdgcn_s_barrier();                                             \
    asm volatile("" ::: "memory");                                            \
  }

#define COMPUTE(ACC, cur)                                                     \
  {                                                                           \
    const __bf16* As_ = &ldsA[cur][(warp_m * 64 + fr) * 64];                  \
    const __bf16* Bs_ = &ldsB[cur][(warp_n * 64 + fr) * 64];                  \
    _Pragma("unroll") for (int kk = 0; kk < 2; ++kk) {                        \
      const int pg_ = ((kk * 4 + fq) ^ (fr & 7)) * 8;                         \
      bf16x8 af[4], bfv[4];                                                   \
      _Pragma("unroll") for (int m = 0; m < 4; ++m)                           \
          af[m] = *(const bf16x8*)(As_ + m * 16 * 64 + pg_);                  \
      _Pragma("unroll") for (int n = 0; n < 4; ++n)                           \
          bfv[n] = *(const bf16x8*)(Bs_ + n * 16 * 64 + pg_);                 \
      __builtin_amdgcn_s_setprio(1);                                          \
      _Pragma("unroll") for (int m = 0; m < 4; ++m)                           \
          _Pragma("unroll") for (int n = 0; n < 4; ++n)                       \
              ACC[m][n] = __builtin_amdgcn_mfma_f32_16x16x32_bf16(            \
                  af[m], bfv[n], ACC[m][n], 0, 0, 0);                         \
      __builtin_amdgcn_s_setprio(0);                                          \
    }                                                                         \
  }

  f32x4 accr[4][4], accg[4][4];
#pragma unroll
  for (int m = 0; m < 4; ++m)
#pragma unroll
    for (int n = 0; n < 4; ++n) {
      accr[m][n] = (f32x4){0.f, 0.f, 0.f, 0.f};
      accg[m][n] = (f32x4){0.f, 0.f, 0.f, 0.f};
    }

  STG(0, 0);
  for (int vt = 0; vt < 8; ++vt) {
    const int cur = vt & 1;
    STG(vt + 1, cur ^ 1);
    asm volatile("s_waitcnt vmcnt(8)" ::: "memory");
    BARF;
    COMPUTE(accr, cur);
    BARF;
  }
  for (int vt = 8; vt < 24; ++vt) {
    const int cur = vt & 1;
    if (vt + 1 < 24) {
      STG(vt + 1, cur ^ 1);
      asm volatile("s_waitcnt vmcnt(8)" ::: "memory");
    } else {
      asm volatile("s_waitcnt vmcnt(0)" ::: "memory");
    }
    BARF;
    COMPUTE(accg, cur);
    BARF;
  }
#undef STG
#undef COMPUTE
#undef BARF

#pragma unroll
  for (int n = 0; n < 4; ++n) {
    const int col = col0 + warp_n * 64 + n * 16 + fr;
    const float bias = gb[col];
#pragma unroll
    for (int m = 0; m < 4; ++m) {
#pragma unroll
      for (int j = 0; j < 4; ++j) {
        const int row = row0 + warp_m * 64 + m * 16 + fq * 4 + j;
        const size_t o = (size_t)row * EMBED + col;
        const float gt = 1.0f / (1.0f + __expf(-(accg[m][n][j] + bias)));
        const float xv = (float)xb[o];
        out[o] = gt * xv + (1.0f - gt) * accr[m][n][j];
      }
    }
  }
}

extern "C" void kernel_launch(void* const* d_in, const int* in_sizes, int n_in,
                              void* d_out, int out_size, void* d_ws,
                              size_t ws_size, hipStream_t stream) {
  const float* x = (const float*)d_in[0];
  const float* mb = (const float*)d_in[1];
  const float* gw = (const float*)d_in[2];
  const float* gb = (const float*)d_in[3];
  float* out = (float*)d_out;

  char* ws = (char*)d_ws;
  __bf16* xb = (__bf16*)(ws);                   // 16384*1024*2 = 33,554,432
  __bf16* mbb = (__bf16*)(ws + 33554432);       // 512*1024*2  =  1,048,576
  __bf16* mbt = (__bf16*)(ws + 34603008);       // 1024*512*2  =  1,048,576
  __bf16* gwb = (__bf16*)(ws + 35651584);       // 1024*1024*2 =  2,097,152
  __bf16* s1 = (__bf16*)(ws + 37748736);        // 16384*512*2 = 16,777,216
  // total 54,525,952 bytes

  cast_bf16_kernel<<<256, 256, 0, stream>>>(mb, mbb, 65536);
  cast_bf16_kernel<<<512, 256, 0, stream>>>(gw, gwb, 131072);
  transpose_mb_kernel<<<2048, 256, 0, stream>>>(mb, mbt);
  // scores + softmax + x-cast fused (writes xb and normalized s1)
  scores_mega_kernel<<<256, 512, 0, stream>>>(x, mbb, xb, s1);
  dual_fused128_kernel<<<1024, 256, 0, stream>>>(s1, xb, mbt, gwb, gb, out);
}